// Round 9
// baseline (255.647 us; speedup 1.0000x reference)
//
#include <hip/hip_runtime.h>
#include <math.h>

typedef float f4 __attribute__((ext_vector_type(4)));

#define TOKENS 16384
#define DIM    4096
#define NE     64
#define KTOP   8
#define BM     32                 // tokens per block
#define BK     32
#define NGRP   4                  // single-wave K-split groups per block
#define KRANGE (DIM / NGRP)       // 1024 K per group
#define NTILE  (KRANGE / BK)      // 32 tiles per group
#define NT     256
#define NBLK   (TOKENS / BM)      // 512 blocks = 2 blocks/CU -> 2 waves/SIMD

// Gate GEMM + softmax + top-8. Block = 4 independent single-wave groups, each
// covering 1024 of K with a 4x8-per-thread register tile. Groups stage their
// own tiles (same-wave in-order LDS => NO barriers in the main loop; round-8
// proven). Sized for ~110 VGPR (acc 32 + prefetch 48) on the reliable
// 256-thread codegen path — rounds 2/4/5/6/8 showed every config needing
// >128 regs or using >=512-thread blocks spills (WRITE_SIZE blowup).
//
// LDS per group: As[32k][32m] (1024 w) | Bs[32k][64e] (2048 w) = 12 KB.
// Quad-rotation swizzle word = kk*S + ((m + 4*kk) mod S):
//   A reads (8 token-quads x 16B) hit all 32 banks -> conflict-free;
//   B reads 2-way (free, m136); staging writes 4-way (48 instrs/tile, minor).
__global__ __launch_bounds__(NT) void gate_topk_kernel(
    const float* __restrict__ x, const float* __restrict__ W,
    const float* __restrict__ bias, float* __restrict__ idx_out,
    float* __restrict__ val_out, float* __restrict__ blocksums)
{
    __shared__ float smem[NGRP * 3072];   // 48 KB
    __shared__ float bsum[NGRP];

    const int tid = threadIdx.x;
    const int g   = tid >> 6;      // K-split group = wave
    const int t   = tid & 63;
    const int k4  = t & 7;         // staging f4-chunk along K (covers 32 k)
    const int r   = t >> 3;        // staging row low bits (rows r+8s)
    const int te  = t & 7;         // compute: expert octet
    const int tq  = t >> 3;        // compute: token quad
    const int row0 = blockIdx.x * BM;

    float* As = &smem[g * 3072];
    float* Bs = As + 1024;

    const float* xa = x + (size_t)(row0 + r) * DIM + g * KRANGE + (k4 << 2);
    const float* wb = W + (size_t)r * DIM + g * KRANGE + (k4 << 2);

    float acc[4][8] = {};
    f4 fa[4], fb[8];

#define LOAD(kt) do {                                                    \
        _Pragma("unroll")                                                \
        for (int s = 0; s < 4; ++s)                                      \
            fa[s] = *(const f4*)(xa + (size_t)(s << 3) * DIM + (kt) * BK); \
        _Pragma("unroll")                                                \
        for (int s = 0; s < 8; ++s)                                      \
            fb[s] = *(const f4*)(wb + (size_t)(s << 3) * DIM + (kt) * BK); \
    } while (0)

#define WRITE_TILE() do {                                                \
        _Pragma("unroll")                                                \
        for (int j = 0; j < 4; ++j) {                                    \
            const int kk = (k4 << 2) + j;                                \
            _Pragma("unroll")                                            \
            for (int s = 0; s < 4; ++s)                                  \
                As[kk * 32 + ((r + (s << 3) + (kk << 2)) & 31)] = fa[s][j]; \
            _Pragma("unroll")                                            \
            for (int s = 0; s < 8; ++s)                                  \
                Bs[kk * 64 + ((r + (s << 3) + (kk << 2)) & 63)] = fb[s][j]; \
        }                                                                \
    } while (0)

#define COMPUTE() do {                                                   \
        _Pragma("unroll")                                                \
        for (int kk = 0; kk < BK; ++kk) {                                \
            const f4 A  = *(const f4*)&As[kk * 32 + (((tq + kk) << 2) & 31)]; \
            const f4 B0 = *(const f4*)&Bs[kk * 64 + (((te << 3) + (kk << 2)) & 63)]; \
            const f4 B1 = *(const f4*)&Bs[kk * 64 + (((te << 3) + 4 + (kk << 2)) & 63)]; \
            _Pragma("unroll")                                            \
            for (int i = 0; i < 4; ++i) {                                \
                _Pragma("unroll")                                        \
                for (int j = 0; j < 4; ++j) {                            \
                    acc[i][j]     = fmaf(A[i], B0[j], acc[i][j]);        \
                    acc[i][j + 4] = fmaf(A[i], B1[j], acc[i][j + 4]);    \
                }                                                        \
            }                                                            \
        }                                                                \
    } while (0)

    LOAD(0);
    WRITE_TILE();
    for (int kt = 0; kt < NTILE - 1; ++kt) {
        LOAD(kt + 1);      // prefetch next tile into regs (flies under COMPUTE)
        COMPUTE();         // reads current tile (in-order before next writes)
        WRITE_TILE();      // same-wave program order protects the overwrite
    }
    COMPUTE();             // last tile

#undef LOAD
#undef WRITE_TILE
#undef COMPUTE

    // ---- partial logits P[g][32][64] overlay the group's region (same-wave
    // in-order LDS: our last COMPUTE's reads complete before these writes).
#pragma unroll
    for (int i = 0; i < 4; ++i) {
        const int pr = ((tq << 2) + i) << 6;
        f4 v0 = { acc[i][0], acc[i][1], acc[i][2], acc[i][3] };
        f4 v1 = { acc[i][4], acc[i][5], acc[i][6], acc[i][7] };
        *(f4*)&As[pr + (te << 3)]     = v0;
        *(f4*)&As[pr + (te << 3) + 4] = v1;
    }
    __syncthreads();   // the only barrier: all groups' P visible block-wide

    // ---- epilogue: wave g handles tokens 8g..8g+7; lane = expert
    const int lane = t;
    const float bv = bias[lane];
    float wsum = 0.0f;
#pragma unroll
    for (int tt = 0; tt < 8; ++tt) {
        const int tl = (g << 3) + tt;
        const int token = row0 + tl;
        const float logit = smem[0 * 3072 + tl * 64 + lane]
                          + smem[1 * 3072 + tl * 64 + lane]
                          + smem[2 * 3072 + tl * 64 + lane]
                          + smem[3 * 3072 + tl * 64 + lane] + bv;
        float mx = logit;
#pragma unroll
        for (int off = 32; off > 0; off >>= 1)
            mx = fmaxf(mx, __shfl_xor(mx, off, 64));
        const float p = expf(logit - mx);
        float s = p;
#pragma unroll
        for (int off = 32; off > 0; off >>= 1)
            s += __shfl_xor(s, off, 64);           // identical tree on all lanes
        const float rs = 1.0f / s;
        float pv = p;
#pragma unroll
        for (int j = 0; j < KTOP; ++j) {
            float v = pv; int e = lane;
#pragma unroll
            for (int off = 1; off < 64; off <<= 1) {   // argmax, lower idx wins ties
                const float v2 = __shfl_xor(v, off, 64);
                const int   e2 = __shfl_xor(e, off, 64);
                if (v2 > v || (v2 == v && e2 < e)) { v = v2; e = e2; }
            }
            const float val = v * rs;
            if (lane == j) {
                idx_out[token * KTOP + j] = (float)e;   // d_out read back as flat f32
                val_out[token * KTOP + j] = val;        // raw; normalized by K2
            }
            if (lane == e) pv = -1.0f;
            wsum += val;                                // uniform across lanes
        }
    }
    if (lane == 0) bsum[g] = wsum;
    __syncthreads();
    if (tid == 0)
        blocksums[blockIdx.x] = bsum[0] + bsum[1] + bsum[2] + bsum[3];
}

// K2: weights = vals / sum(all vals). Every thread computes the same serial sum
// of 512 partials (uniform -> scalarized, deterministic), then divides in place.
__global__ __launch_bounds__(256) void scale_kernel(
    const float* __restrict__ blocksums, float* __restrict__ vals)
{
    float total = 0.0f;
    for (int i = 0; i < NBLK / 4; ++i) {
        const f4 v = *(const f4*)(blocksums + i * 4);
        total += v[0] + v[1] + v[2] + v[3];
    }
    const int i = blockIdx.x * blockDim.x + threadIdx.x;
    vals[i] = vals[i] / total;
}

extern "C" void kernel_launch(void* const* d_in, const int* in_sizes, int n_in,
                              void* d_out, int out_size, void* d_ws, size_t ws_size,
                              hipStream_t stream)
{
    const float* x = (const float*)d_in[0];
    const float* W = (const float*)d_in[1];
    const float* b = (const float*)d_in[2];
    float* idx_out = (float*)d_out;
    float* val_out = idx_out + (size_t)TOKENS * KTOP;
    float* blocksums = (float*)d_ws;

    gate_topk_kernel<<<NBLK, NT, 0, stream>>>(x, W, b, idx_out, val_out, blocksums);
    scale_kernel<<<(TOKENS * KTOP) / 256, 256, 0, stream>>>(blocksums, val_out);
}